// Round 1
// baseline (1779.194 us; speedup 1.0000x reference)
//
#include <hip/hip_runtime.h>
#include <math.h>

#define B_ 2
#define T_ 2048
#define D_ 1024
#define H_ 16
#define DK 64
#define BH_ (B_*H_)

__device__ __forceinline__ float dot4(float4 a, float4 b) {
    return a.x*b.x + a.y*b.y + a.z*b.z + a.w*b.w;
}

// ---------------------------------------------------------------------------
// Kernel 1: per-head QKV projection.
// grid (B*H, T/64), block 256.  q/k/v layout: [B*H, T, DK]
// ---------------------------------------------------------------------------
__global__ __launch_bounds__(256) void qkv_kernel(
    const float* __restrict__ x,
    const float* __restrict__ Wq, const float* __restrict__ Wk,
    const float* __restrict__ Wv,
    float* __restrict__ q, float* __restrict__ k, float* __restrict__ v)
{
    __shared__ float ws[3][64][68];   // weights for this head, padded
    const int bh = blockIdx.x;
    const int b  = bh / H_, h = bh % H_;
    const int t0 = blockIdx.y * 64;
    const int tid = threadIdx.x;

    // stage the three 64x64 weight matrices (coalesced float4)
    const float* wsrc0 = Wq + (size_t)h*DK*DK;
    const float* wsrc1 = Wk + (size_t)h*DK*DK;
    const float* wsrc2 = Wv + (size_t)h*DK*DK;
    for (int i = tid; i < 1024; i += 256) {
        int row = i >> 4, c4 = (i & 15) * 4;
        *(float4*)&ws[0][row][c4] = *(const float4*)&wsrc0[row*DK + c4];
        *(float4*)&ws[1][row][c4] = *(const float4*)&wsrc1[row*DK + c4];
        *(float4*)&ws[2][row][c4] = *(const float4*)&wsrc2[row*DK + c4];
    }
    __syncthreads();

    const int kk = tid & 63;        // output column (lane)
    const int g  = tid >> 6;        // wave id -> t offset

    float acc0[16], acc1[16], acc2[16];
    #pragma unroll
    for (int i = 0; i < 16; ++i) { acc0[i]=0.f; acc1[i]=0.f; acc2[i]=0.f; }

    for (int d4 = 0; d4 < 16; ++d4) {
        float4 w0 = *(float4*)&ws[0][kk][d4*4];
        float4 w1 = *(float4*)&ws[1][kk][d4*4];
        float4 w2 = *(float4*)&ws[2][kk][d4*4];
        #pragma unroll
        for (int i = 0; i < 16; ++i) {
            int t = t0 + g + i*4;
            float4 x4 = *(const float4*)&x[((size_t)b*T_ + t)*D_ + h*DK + d4*4];
            acc0[i] += dot4(x4, w0);
            acc1[i] += dot4(x4, w1);
            acc2[i] += dot4(x4, w2);
        }
    }
    #pragma unroll
    for (int i = 0; i < 16; ++i) {
        int t = t0 + g + i*4;
        size_t o = ((size_t)bh*T_ + t)*DK + kk;
        q[o] = acc0[i];
        k[o] = acc1[i];
        v[o] = acc2[i];
    }
}

// ---------------------------------------------------------------------------
// Kernel 2: causal flash attention, fp32.
// grid (T/16, B*H), block 256 = 4 waves; each wave owns 4 consecutive queries.
// Output layout: [B, T, H*DK] (= [B*T, D], ready for the final GEMM)
// ---------------------------------------------------------------------------
__global__ __launch_bounds__(256) void attn_kernel(
    const float* __restrict__ q, const float* __restrict__ k,
    const float* __restrict__ v, float* __restrict__ aout)
{
    __shared__ float Ks[64][68];
    __shared__ float Vs[64][68];
    __shared__ float Qs[16][68];

    const int qt  = blockIdx.x;      // 16-query tile
    const int bh  = blockIdx.y;
    const int b   = bh / H_, h = bh % H_;
    const int tid = threadIdx.x;
    const int wave = tid >> 6, lane = tid & 63;

    // stage 16 query rows
    {
        int row = tid >> 4, c4 = (tid & 15) * 4;
        *(float4*)&Qs[row][c4] =
            *(const float4*)&q[((size_t)bh*T_ + qt*16 + row)*DK + c4];
    }

    const int q0 = qt*16 + wave*4;   // this wave's first query
    float m0=-INFINITY, m1=-INFINITY, m2=-INFINITY, m3=-INFINITY;
    float l0=0.f, l1=0.f, l2=0.f, l3=0.f;
    float a0=0.f, a1=0.f, a2=0.f, a3=0.f;   // O accumulator, dim = lane

    const int ntiles = qt/4 + 1;     // keys 0 .. qt*16+15 inclusive
    for (int kt = 0; kt < ntiles; ++kt) {
        __syncthreads();
        for (int i = tid; i < 1024; i += 256) {
            int row = i >> 4, c4 = (i & 15) * 4;
            size_t g = ((size_t)bh*T_ + kt*64 + row)*DK + c4;
            *(float4*)&Ks[row][c4] = *(const float4*)&k[g];
            *(float4*)&Vs[row][c4] = *(const float4*)&v[g];
        }
        __syncthreads();

        // scores: lane j = key kt*64+lane
        float s0=0.f, s1=0.f, s2=0.f, s3=0.f;
        #pragma unroll 4
        for (int d4 = 0; d4 < 16; ++d4) {
            float4 k4 = *(float4*)&Ks[lane][d4*4];
            float4 qa = *(float4*)&Qs[wave*4+0][d4*4];
            float4 qb = *(float4*)&Qs[wave*4+1][d4*4];
            float4 qc = *(float4*)&Qs[wave*4+2][d4*4];
            float4 qd = *(float4*)&Qs[wave*4+3][d4*4];
            s0 += dot4(qa, k4); s1 += dot4(qb, k4);
            s2 += dot4(qc, k4); s3 += dot4(qd, k4);
        }
        const int key = kt*64 + lane;
        s0 = (key <= q0+0) ? s0*0.125f : -INFINITY;
        s1 = (key <= q0+1) ? s1*0.125f : -INFINITY;
        s2 = (key <= q0+2) ? s2*0.125f : -INFINITY;
        s3 = (key <= q0+3) ? s3*0.125f : -INFINITY;

        // online softmax, per query
        #define SOFTMAX_STEP(S, M, L, A)                                   \
        {                                                                  \
            float mx = S;                                                  \
            for (int off = 1; off < 64; off <<= 1)                         \
                mx = fmaxf(mx, __shfl_xor(mx, off));                       \
            float mn = fmaxf(M, mx);                                       \
            S = __expf(S - mn);              /* masked -> 0 */             \
            float al = __expf(M - mn);                                     \
            float ps = S;                                                  \
            for (int off = 1; off < 64; off <<= 1)                         \
                ps += __shfl_xor(ps, off);                                 \
            L = L*al + ps;                                                 \
            M = mn;                                                        \
            A *= al;                                                       \
        }
        SOFTMAX_STEP(s0, m0, l0, a0)
        SOFTMAX_STEP(s1, m1, l1, a1)
        SOFTMAX_STEP(s2, m2, l2, a2)
        SOFTMAX_STEP(s3, m3, l3, a3)
        #undef SOFTMAX_STEP

        // PV: acc[d=lane] += sum_j p_j * V[j][lane]
        #pragma unroll
        for (int j = 0; j < 64; ++j) {
            float vj = Vs[j][lane];
            a0 += __shfl(s0, j) * vj;
            a1 += __shfl(s1, j) * vj;
            a2 += __shfl(s2, j) * vj;
            a3 += __shfl(s3, j) * vj;
        }
    }

    size_t o = ((size_t)b*T_ + q0)*D_ + h*DK + lane;
    aout[o]        = a0 / l0;
    aout[o + D_]   = a1 / l1;
    aout[o + 2*D_] = a2 / l2;
    aout[o + 3*D_] = a3 / l3;
}

// ---------------------------------------------------------------------------
// Kernel 3: out = A @ Wp^T + bp.   A:[4096,1024], Wp:[1024,1024]
// grid (64,16), block 256, 64x64 tiles, 4x4 outputs/thread.
// ---------------------------------------------------------------------------
__global__ __launch_bounds__(256) void proj_kernel(
    const float* __restrict__ A, const float* __restrict__ Wp,
    const float* __restrict__ bp, float* __restrict__ out)
{
    __shared__ float As[64][68];
    __shared__ float Bs[64][68];
    const int m0 = blockIdx.x * 64, n0 = blockIdx.y * 64;
    const int tid = threadIdx.x;
    const int tx = tid & 15, ty = tid >> 4;

    float acc[4][4] = {};

    for (int k0 = 0; k0 < 1024; k0 += 64) {
        __syncthreads();
        for (int i = tid; i < 1024; i += 256) {
            int row = i >> 4, c4 = (i & 15) * 4;
            *(float4*)&As[row][c4] = *(const float4*)&A [(size_t)(m0+row)*1024 + k0 + c4];
            *(float4*)&Bs[row][c4] = *(const float4*)&Wp[(size_t)(n0+row)*1024 + k0 + c4];
        }
        __syncthreads();
        for (int k4 = 0; k4 < 16; ++k4) {
            float4 a4[4], w4[4];
            #pragma unroll
            for (int i = 0; i < 4; ++i) a4[i] = *(float4*)&As[ty*4 + i][k4*4];
            #pragma unroll
            for (int j = 0; j < 4; ++j) w4[j] = *(float4*)&Bs[tx + 16*j][k4*4];
            #pragma unroll
            for (int i = 0; i < 4; ++i)
                #pragma unroll
                for (int j = 0; j < 4; ++j)
                    acc[i][j] += dot4(a4[i], w4[j]);
        }
    }

    #pragma unroll
    for (int i = 0; i < 4; ++i) {
        int m = m0 + ty*4 + i;
        #pragma unroll
        for (int j = 0; j < 4; ++j) {
            int n = n0 + tx + 16*j;
            out[(size_t)m*1024 + n] = acc[i][j] + bp[n];
        }
    }
}

// ---------------------------------------------------------------------------
extern "C" void kernel_launch(void* const* d_in, const int* in_sizes, int n_in,
                              void* d_out, int out_size, void* d_ws, size_t ws_size,
                              hipStream_t stream)
{
    const float* x  = (const float*)d_in[0];
    const float* Wq = (const float*)d_in[1];
    const float* Wk = (const float*)d_in[2];
    const float* Wv = (const float*)d_in[3];
    const float* Wp = (const float*)d_in[4];
    const float* bp = (const float*)d_in[5];
    float* out = (float*)d_out;

    const size_t per = (size_t)BH_ * T_ * DK;   // 4,194,304 floats = 16 MB
    float* qws = (float*)d_ws;
    float* kws = qws + per;
    float* vws = kws + per;
    float* aws = vws + per;                      // [B*T, D]

    qkv_kernel<<<dim3(BH_, T_/64), 256, 0, stream>>>(x, Wq, Wk, Wv, qws, kws, vws);
    attn_kernel<<<dim3(T_/16, BH_), 256, 0, stream>>>(qws, kws, vws, aws);
    proj_kernel<<<dim3(64, 16), 256, 0, stream>>>(aws, Wp, bp, out);
}

// Round 2
// 401.610 us; speedup vs baseline: 4.4302x; 4.4302x over previous
//
#include <hip/hip_runtime.h>
#include <math.h>

#define B_ 2
#define T_ 2048
#define D_ 1024
#define H_ 16
#define DK 64
#define BH_ (B_*H_)

typedef __attribute__((ext_vector_type(8))) short short8;   // 8 bf16 = 4 VGPRs
typedef __attribute__((ext_vector_type(4))) float fragC;    // MFMA C/D

__device__ __forceinline__ float dot4(float4 a, float4 b) {
    return a.x*b.x + a.y*b.y + a.z*b.z + a.w*b.w;
}

__device__ __forceinline__ unsigned short f2bf(float x) {
    union { float f; unsigned u; } c; c.f = x;
    unsigned r = c.u + 0x7fff + ((c.u >> 16) & 1);   // RNE
    return (unsigned short)(r >> 16);
}

// ---------------------------------------------------------------------------
// Kernel 1: per-head QKV projection -> bf16.  q,k: [BH,T,DK]; v transposed: [BH,DK,T]
// grid (B*H, T/64), block 256.
// ---------------------------------------------------------------------------
__global__ __launch_bounds__(256) void qkv_kernel(
    const float* __restrict__ x,
    const float* __restrict__ Wq, const float* __restrict__ Wk,
    const float* __restrict__ Wv,
    unsigned short* __restrict__ q, unsigned short* __restrict__ k,
    unsigned short* __restrict__ vt)
{
    __shared__ float ws[3][64][68];
    const int bh = blockIdx.x;
    const int b  = bh / H_, h = bh % H_;
    const int t0 = blockIdx.y * 64;
    const int tid = threadIdx.x;

    const float* wsrc0 = Wq + (size_t)h*DK*DK;
    const float* wsrc1 = Wk + (size_t)h*DK*DK;
    const float* wsrc2 = Wv + (size_t)h*DK*DK;
    for (int i = tid; i < 1024; i += 256) {
        int row = i >> 4, c4 = (i & 15) * 4;
        *(float4*)&ws[0][row][c4] = *(const float4*)&wsrc0[row*DK + c4];
        *(float4*)&ws[1][row][c4] = *(const float4*)&wsrc1[row*DK + c4];
        *(float4*)&ws[2][row][c4] = *(const float4*)&wsrc2[row*DK + c4];
    }
    __syncthreads();

    const int kk = tid & 63;
    const int g  = tid >> 6;

    float acc0[16], acc1[16], acc2[16];
    #pragma unroll
    for (int i = 0; i < 16; ++i) { acc0[i]=0.f; acc1[i]=0.f; acc2[i]=0.f; }

    for (int d4 = 0; d4 < 16; ++d4) {
        float4 w0 = *(float4*)&ws[0][kk][d4*4];
        float4 w1 = *(float4*)&ws[1][kk][d4*4];
        float4 w2 = *(float4*)&ws[2][kk][d4*4];
        #pragma unroll
        for (int i = 0; i < 16; ++i) {
            int t = t0 + g + i*4;
            float4 x4 = *(const float4*)&x[((size_t)b*T_ + t)*D_ + h*DK + d4*4];
            acc0[i] += dot4(x4, w0);
            acc1[i] += dot4(x4, w1);
            acc2[i] += dot4(x4, w2);
        }
    }
    // q,k: bf16 direct store
    #pragma unroll
    for (int i = 0; i < 16; ++i) {
        int t = t0 + g + i*4;
        size_t o = ((size_t)bh*T_ + t)*DK + kk;
        q[o] = f2bf(acc0[i]);
        k[o] = f2bf(acc1[i]);
    }
    // v: transpose via LDS then bf16 store to [BH, DK, T]
    __syncthreads();                         // everyone done reading ws
    #pragma unroll
    for (int i = 0; i < 16; ++i)
        ws[0][g + i*4][kk] = acc2[i];        // [t_local][d]
    __syncthreads();
    {
        const int d  = tid >> 2;             // 0..63
        const int c0 = (tid & 3) * 16;       // t_local base
        unsigned int pk[8];
        #pragma unroll
        for (int jj = 0; jj < 8; ++jj) {
            unsigned lo = f2bf(ws[0][c0 + 2*jj][d]);
            unsigned hi = f2bf(ws[0][c0 + 2*jj + 1][d]);
            pk[jj] = lo | (hi << 16);
        }
        unsigned short* dst = &vt[((size_t)bh*DK + d)*T_ + t0 + c0];
        ((uint4*)dst)[0] = make_uint4(pk[0], pk[1], pk[2], pk[3]);
        ((uint4*)dst)[1] = make_uint4(pk[4], pk[5], pk[6], pk[7]);
    }
}

// ---------------------------------------------------------------------------
// Kernel 2: causal flash attention, bf16 MFMA.
// grid (T/64, B*H), block 256 = 4 waves; wave w owns 16 queries.
// aout: [B, T, D] fp32
// ---------------------------------------------------------------------------
__global__ __launch_bounds__(256) void attn_kernel(
    const unsigned short* __restrict__ q, const unsigned short* __restrict__ k,
    const unsigned short* __restrict__ vt, float* __restrict__ aout)
{
    __shared__ unsigned short Ks[64][72];       // [key][d]
    __shared__ unsigned short Vs[64][72];       // [d][key]  (V^T)
    __shared__ unsigned short Ps[4][16][72];    // per-wave P transpose buffer

    const int qt  = (gridDim.x - 1) - blockIdx.x;   // longest blocks first
    const int bh  = blockIdx.y;
    const int b   = bh >> 4, h = bh & 15;
    const int tid = threadIdx.x;
    const int wave = tid >> 6, lane = tid & 63;
    const int n = lane & 15, quad = lane >> 4;

    const size_t qkbase = (size_t)bh * T_ * DK;
    const int q0 = qt*64 + wave*16;

    // Q fragments (A-layout: m=lane&15, k=quad*8+j), loaded once
    short8 qf0 = *(const short8*)&q[qkbase + (size_t)(q0 + n)*DK + quad*8];
    short8 qf1 = *(const short8*)&q[qkbase + (size_t)(q0 + n)*DK + 32 + quad*8];

    fragC o0 = {0.f,0.f,0.f,0.f}, o1 = o0, o2 = o0, o3 = o0;
    float m_[4] = {-INFINITY,-INFINITY,-INFINITY,-INFINITY};
    float l_[4] = {0.f,0.f,0.f,0.f};

    // staging assignment
    const int srow = tid >> 2;            // 0..63
    const int scol = (tid & 3) * 16;      // 0..48
    const unsigned short* kg = &k[qkbase + (size_t)srow*DK + scol];
    const unsigned short* vg = &vt[((size_t)bh*DK + srow)*T_ + scol];

    const int nt = qt + 1;
    for (int kt = 0; kt < nt; ++kt) {
        const int k0 = kt * 64;
        __syncthreads();
        *(short8*)&Ks[srow][scol]     = *(const short8*)&kg[(size_t)k0*DK];
        *(short8*)&Ks[srow][scol + 8] = *(const short8*)&kg[(size_t)k0*DK + 8];
        *(short8*)&Vs[srow][scol]     = *(const short8*)&vg[k0];
        *(short8*)&Vs[srow][scol + 8] = *(const short8*)&vg[k0 + 8];
        __syncthreads();

        // S = Q·K^T : 4 tiles of 16 keys
        fragC st[4];
        #pragma unroll
        for (int t = 0; t < 4; ++t) {
            short8 kf0 = *(const short8*)&Ks[t*16 + n][quad*8];
            short8 kf1 = *(const short8*)&Ks[t*16 + n][32 + quad*8];
            fragC c = {0.f,0.f,0.f,0.f};
            c = __builtin_amdgcn_mfma_f32_16x16x32_bf16(qf0, kf0, c, 0, 0, 0);
            c = __builtin_amdgcn_mfma_f32_16x16x32_bf16(qf1, kf1, c, 0, 0, 0);
            st[t] = c;
        }

        // online softmax (exp2 with folded log2e * 1/sqrt(dk))
        const float sc = 0.125f * 1.44269504088896340736f;
        float p[4][4], al[4];
        #pragma unroll
        for (int r = 0; r < 4; ++r) {
            const int qrow = q0 + quad*4 + r;
            #pragma unroll
            for (int t = 0; t < 4; ++t) {
                float sv = st[t][r] * sc;
                p[t][r] = (k0 + t*16 + n > qrow) ? -INFINITY : sv;
            }
            float mr = fmaxf(fmaxf(p[0][r], p[1][r]), fmaxf(p[2][r], p[3][r]));
            mr = fmaxf(mr, __shfl_xor(mr, 1));
            mr = fmaxf(mr, __shfl_xor(mr, 2));
            mr = fmaxf(mr, __shfl_xor(mr, 4));
            mr = fmaxf(mr, __shfl_xor(mr, 8));
            const float mn = fmaxf(m_[r], mr);
            al[r] = exp2f(m_[r] - mn);
            m_[r] = mn;
            float rs = 0.f;
            #pragma unroll
            for (int t = 0; t < 4; ++t) { p[t][r] = exp2f(p[t][r] - mn); rs += p[t][r]; }
            rs += __shfl_xor(rs, 1);
            rs += __shfl_xor(rs, 2);
            rs += __shfl_xor(rs, 4);
            rs += __shfl_xor(rs, 8);
            l_[r] = l_[r]*al[r] + rs;
        }

        // rescale O, write P (bf16) to wave-private LDS in A-layout order
        #pragma unroll
        for (int r = 0; r < 4; ++r) {
            o0[r] *= al[r]; o1[r] *= al[r]; o2[r] *= al[r]; o3[r] *= al[r];
            #pragma unroll
            for (int t = 0; t < 4; ++t)
                Ps[wave][quad*4 + r][t*16 + n] = f2bf(p[t][r]);
        }

        short8 pf0 = *(const short8*)&Ps[wave][n][quad*8];        // keys 0..31
        short8 pf1 = *(const short8*)&Ps[wave][n][32 + quad*8];   // keys 32..63

        // O += P·V  (V^T rows give B-layout directly)
        o0 = __builtin_amdgcn_mfma_f32_16x16x32_bf16(pf0, *(const short8*)&Vs[n     ][quad*8],      o0, 0,0,0);
        o0 = __builtin_amdgcn_mfma_f32_16x16x32_bf16(pf1, *(const short8*)&Vs[n     ][32 + quad*8], o0, 0,0,0);
        o1 = __builtin_amdgcn_mfma_f32_16x16x32_bf16(pf0, *(const short8*)&Vs[16 + n][quad*8],      o1, 0,0,0);
        o1 = __builtin_amdgcn_mfma_f32_16x16x32_bf16(pf1, *(const short8*)&Vs[16 + n][32 + quad*8], o1, 0,0,0);
        o2 = __builtin_amdgcn_mfma_f32_16x16x32_bf16(pf0, *(const short8*)&Vs[32 + n][quad*8],      o2, 0,0,0);
        o2 = __builtin_amdgcn_mfma_f32_16x16x32_bf16(pf1, *(const short8*)&Vs[32 + n][32 + quad*8], o2, 0,0,0);
        o3 = __builtin_amdgcn_mfma_f32_16x16x32_bf16(pf0, *(const short8*)&Vs[48 + n][quad*8],      o3, 0,0,0);
        o3 = __builtin_amdgcn_mfma_f32_16x16x32_bf16(pf1, *(const short8*)&Vs[48 + n][32 + quad*8], o3, 0,0,0);
    }

    // epilogue: divide by l, store fp32 [B,T,D]
    #pragma unroll
    for (int r = 0; r < 4; ++r) {
        const float inv = 1.0f / l_[r];
        size_t o = ((size_t)b*T_ + q0 + quad*4 + r)*D_ + h*DK + n;
        aout[o]      = o0[r] * inv;
        aout[o + 16] = o1[r] * inv;
        aout[o + 32] = o2[r] * inv;
        aout[o + 48] = o3[r] * inv;
    }
}

// ---------------------------------------------------------------------------
// Kernel 3: out = A @ Wp^T + bp.   A:[4096,1024] fp32, Wp:[1024,1024]
// ---------------------------------------------------------------------------
__global__ __launch_bounds__(256) void proj_kernel(
    const float* __restrict__ A, const float* __restrict__ Wp,
    const float* __restrict__ bp, float* __restrict__ out)
{
    __shared__ float As[64][68];
    __shared__ float Bs[64][68];
    const int m0 = blockIdx.x * 64, n0 = blockIdx.y * 64;
    const int tid = threadIdx.x;
    const int tx = tid & 15, ty = tid >> 4;

    float acc[4][4] = {};

    for (int k0 = 0; k0 < 1024; k0 += 64) {
        __syncthreads();
        for (int i = tid; i < 1024; i += 256) {
            int row = i >> 4, c4 = (i & 15) * 4;
            *(float4*)&As[row][c4] = *(const float4*)&A [(size_t)(m0+row)*1024 + k0 + c4];
            *(float4*)&Bs[row][c4] = *(const float4*)&Wp[(size_t)(n0+row)*1024 + k0 + c4];
        }
        __syncthreads();
        for (int k4 = 0; k4 < 16; ++k4) {
            float4 a4[4], w4[4];
            #pragma unroll
            for (int i = 0; i < 4; ++i) a4[i] = *(float4*)&As[ty*4 + i][k4*4];
            #pragma unroll
            for (int j = 0; j < 4; ++j) w4[j] = *(float4*)&Bs[tx + 16*j][k4*4];
            #pragma unroll
            for (int i = 0; i < 4; ++i)
                #pragma unroll
                for (int j = 0; j < 4; ++j)
                    acc[i][j] += dot4(a4[i], w4[j]);
        }
    }

    #pragma unroll
    for (int i = 0; i < 4; ++i) {
        int m = m0 + ty*4 + i;
        #pragma unroll
        for (int j = 0; j < 4; ++j) {
            int n = n0 + tx + 16*j;
            out[(size_t)m*1024 + n] = acc[i][j] + bp[n];
        }
    }
}

// ---------------------------------------------------------------------------
extern "C" void kernel_launch(void* const* d_in, const int* in_sizes, int n_in,
                              void* d_out, int out_size, void* d_ws, size_t ws_size,
                              hipStream_t stream)
{
    const float* x  = (const float*)d_in[0];
    const float* Wq = (const float*)d_in[1];
    const float* Wk = (const float*)d_in[2];
    const float* Wv = (const float*)d_in[3];
    const float* Wp = (const float*)d_in[4];
    const float* bp = (const float*)d_in[5];
    float* out = (float*)d_out;

    const size_t per = (size_t)BH_ * T_ * DK;     // 4,194,304 elements
    unsigned short* qws  = (unsigned short*)d_ws; // bf16
    unsigned short* kws  = qws + per;
    unsigned short* vtws = kws + per;
    float* aws = (float*)(vtws + per);            // [B*T, D] fp32

    qkv_kernel<<<dim3(BH_, T_/64), 256, 0, stream>>>(x, Wq, Wk, Wv, qws, kws, vtws);
    attn_kernel<<<dim3(T_/64, BH_), 256, 0, stream>>>(qws, kws, vtws, aws);
    proj_kernel<<<dim3(64, 16), 256, 0, stream>>>(aws, Wp, bp, out);
}

// Round 3
// 279.344 us; speedup vs baseline: 6.3692x; 1.4377x over previous
//
#include <hip/hip_runtime.h>
#include <math.h>

#define B_ 2
#define T_ 2048
#define D_ 1024
#define H_ 16
#define DK 64
#define BH_ (B_*H_)

typedef __attribute__((ext_vector_type(8))) short short8;   // 8 bf16 = 4 VGPRs
typedef __attribute__((ext_vector_type(4))) float fragC;    // MFMA C/D

__device__ __forceinline__ float dot4(float4 a, float4 b) {
    return a.x*b.x + a.y*b.y + a.z*b.z + a.w*b.w;
}

__device__ __forceinline__ unsigned short f2bf(float x) {
    union { float f; unsigned u; } c; c.f = x;
    unsigned r = c.u + 0x7fff + ((c.u >> 16) & 1);   // RNE
    return (unsigned short)(r >> 16);
}

// async global->LDS, 16B per lane; LDS dest = wave-uniform base + lane*16
__device__ __forceinline__ void gload_lds16(const void* g, void* l) {
    __builtin_amdgcn_global_load_lds(
        (const __attribute__((address_space(1))) unsigned int*)g,
        (__attribute__((address_space(3))) unsigned int*)l, 16, 0, 0);
}

// ---------------------------------------------------------------------------
// Kernel 1: per-head QKV projection -> bf16.  q,k: [BH,T,DK]; v transposed: [BH,DK,T]
// grid (B*H, T/64), block 256.
// ---------------------------------------------------------------------------
__global__ __launch_bounds__(256) void qkv_kernel(
    const float* __restrict__ x,
    const float* __restrict__ Wq, const float* __restrict__ Wk,
    const float* __restrict__ Wv,
    unsigned short* __restrict__ q, unsigned short* __restrict__ k,
    unsigned short* __restrict__ vt)
{
    __shared__ float ws[3][64][68];
    const int bh = blockIdx.x;
    const int b  = bh / H_, h = bh % H_;
    const int t0 = blockIdx.y * 64;
    const int tid = threadIdx.x;

    const float* wsrc0 = Wq + (size_t)h*DK*DK;
    const float* wsrc1 = Wk + (size_t)h*DK*DK;
    const float* wsrc2 = Wv + (size_t)h*DK*DK;
    for (int i = tid; i < 1024; i += 256) {
        int row = i >> 4, c4 = (i & 15) * 4;
        *(float4*)&ws[0][row][c4] = *(const float4*)&wsrc0[row*DK + c4];
        *(float4*)&ws[1][row][c4] = *(const float4*)&wsrc1[row*DK + c4];
        *(float4*)&ws[2][row][c4] = *(const float4*)&wsrc2[row*DK + c4];
    }
    __syncthreads();

    const int kk = tid & 63;
    const int g  = tid >> 6;

    float acc0[16], acc1[16], acc2[16];
    #pragma unroll
    for (int i = 0; i < 16; ++i) { acc0[i]=0.f; acc1[i]=0.f; acc2[i]=0.f; }

    for (int d4 = 0; d4 < 16; ++d4) {
        float4 w0 = *(float4*)&ws[0][kk][d4*4];
        float4 w1 = *(float4*)&ws[1][kk][d4*4];
        float4 w2 = *(float4*)&ws[2][kk][d4*4];
        #pragma unroll
        for (int i = 0; i < 16; ++i) {
            int t = t0 + g + i*4;
            float4 x4 = *(const float4*)&x[((size_t)b*T_ + t)*D_ + h*DK + d4*4];
            acc0[i] += dot4(x4, w0);
            acc1[i] += dot4(x4, w1);
            acc2[i] += dot4(x4, w2);
        }
    }
    #pragma unroll
    for (int i = 0; i < 16; ++i) {
        int t = t0 + g + i*4;
        size_t o = ((size_t)bh*T_ + t)*DK + kk;
        q[o] = f2bf(acc0[i]);
        k[o] = f2bf(acc1[i]);
    }
    // v: transpose via LDS then bf16 store to [BH, DK, T]
    __syncthreads();
    #pragma unroll
    for (int i = 0; i < 16; ++i)
        ws[0][g + i*4][kk] = acc2[i];        // [t_local][d]
    __syncthreads();
    {
        const int d  = tid >> 2;             // 0..63
        const int c0 = (tid & 3) * 16;       // t_local base
        unsigned int pk[8];
        #pragma unroll
        for (int jj = 0; jj < 8; ++jj) {
            unsigned lo = f2bf(ws[0][c0 + 2*jj][d]);
            unsigned hi = f2bf(ws[0][c0 + 2*jj + 1][d]);
            pk[jj] = lo | (hi << 16);
        }
        unsigned short* dst = &vt[((size_t)bh*DK + d)*T_ + t0 + c0];
        ((uint4*)dst)[0] = make_uint4(pk[0], pk[1], pk[2], pk[3]);
        ((uint4*)dst)[1] = make_uint4(pk[4], pk[5], pk[6], pk[7]);
    }
}

// ---------------------------------------------------------------------------
// Kernel 2: causal flash attention, bf16 MFMA.
// grid (T/64, B*H), block 256 = 4 waves; wave w owns 16 queries.
// aout: [B, T, D] bf16
// ---------------------------------------------------------------------------
__global__ __launch_bounds__(256) void attn_kernel(
    const unsigned short* __restrict__ q, const unsigned short* __restrict__ k,
    const unsigned short* __restrict__ vt, unsigned short* __restrict__ aout)
{
    __shared__ unsigned short Ks[64][72];       // [key][d]
    __shared__ unsigned short Vs[64][72];       // [d][key]  (V^T)
    __shared__ unsigned short Ps[4][16][72];    // per-wave P transpose buffer

    const int qt  = (gridDim.x - 1) - blockIdx.x;   // longest blocks first
    const int bh  = blockIdx.y;
    const int b   = bh >> 4, h = bh & 15;
    const int tid = threadIdx.x;
    const int wave = tid >> 6, lane = tid & 63;
    const int n = lane & 15, quad = lane >> 4;

    const size_t qkbase = (size_t)bh * T_ * DK;
    const int q0 = qt*64 + wave*16;

    short8 qf0 = *(const short8*)&q[qkbase + (size_t)(q0 + n)*DK + quad*8];
    short8 qf1 = *(const short8*)&q[qkbase + (size_t)(q0 + n)*DK + 32 + quad*8];

    fragC o0 = {0.f,0.f,0.f,0.f}, o1 = o0, o2 = o0, o3 = o0;
    float m_[4] = {-INFINITY,-INFINITY,-INFINITY,-INFINITY};
    float l_[4] = {0.f,0.f,0.f,0.f};

    const int srow = tid >> 2;            // 0..63
    const int scol = (tid & 3) * 16;      // 0..48
    const unsigned short* kg = &k[qkbase + (size_t)srow*DK + scol];
    const unsigned short* vg = &vt[((size_t)bh*DK + srow)*T_ + scol];

    const int nt = qt + 1;
    for (int kt = 0; kt < nt; ++kt) {
        const int k0 = kt * 64;
        __syncthreads();
        *(short8*)&Ks[srow][scol]     = *(const short8*)&kg[(size_t)k0*DK];
        *(short8*)&Ks[srow][scol + 8] = *(const short8*)&kg[(size_t)k0*DK + 8];
        *(short8*)&Vs[srow][scol]     = *(const short8*)&vg[k0];
        *(short8*)&Vs[srow][scol + 8] = *(const short8*)&vg[k0 + 8];
        __syncthreads();

        fragC st[4];
        #pragma unroll
        for (int t = 0; t < 4; ++t) {
            short8 kf0 = *(const short8*)&Ks[t*16 + n][quad*8];
            short8 kf1 = *(const short8*)&Ks[t*16 + n][32 + quad*8];
            fragC c = {0.f,0.f,0.f,0.f};
            c = __builtin_amdgcn_mfma_f32_16x16x32_bf16(qf0, kf0, c, 0, 0, 0);
            c = __builtin_amdgcn_mfma_f32_16x16x32_bf16(qf1, kf1, c, 0, 0, 0);
            st[t] = c;
        }

        const float sc = 0.125f * 1.44269504088896340736f;
        float p[4][4], al[4];
        #pragma unroll
        for (int r = 0; r < 4; ++r) {
            const int qrow = q0 + quad*4 + r;
            #pragma unroll
            for (int t = 0; t < 4; ++t) {
                float sv = st[t][r] * sc;
                p[t][r] = (k0 + t*16 + n > qrow) ? -INFINITY : sv;
            }
            float mr = fmaxf(fmaxf(p[0][r], p[1][r]), fmaxf(p[2][r], p[3][r]));
            mr = fmaxf(mr, __shfl_xor(mr, 1));
            mr = fmaxf(mr, __shfl_xor(mr, 2));
            mr = fmaxf(mr, __shfl_xor(mr, 4));
            mr = fmaxf(mr, __shfl_xor(mr, 8));
            const float mn = fmaxf(m_[r], mr);
            al[r] = exp2f(m_[r] - mn);
            m_[r] = mn;
            float rs = 0.f;
            #pragma unroll
            for (int t = 0; t < 4; ++t) { p[t][r] = exp2f(p[t][r] - mn); rs += p[t][r]; }
            rs += __shfl_xor(rs, 1);
            rs += __shfl_xor(rs, 2);
            rs += __shfl_xor(rs, 4);
            rs += __shfl_xor(rs, 8);
            l_[r] = l_[r]*al[r] + rs;
        }

        #pragma unroll
        for (int r = 0; r < 4; ++r) {
            o0[r] *= al[r]; o1[r] *= al[r]; o2[r] *= al[r]; o3[r] *= al[r];
            #pragma unroll
            for (int t = 0; t < 4; ++t)
                Ps[wave][quad*4 + r][t*16 + n] = f2bf(p[t][r]);
        }

        short8 pf0 = *(const short8*)&Ps[wave][n][quad*8];
        short8 pf1 = *(const short8*)&Ps[wave][n][32 + quad*8];

        o0 = __builtin_amdgcn_mfma_f32_16x16x32_bf16(pf0, *(const short8*)&Vs[n     ][quad*8],      o0, 0,0,0);
        o0 = __builtin_amdgcn_mfma_f32_16x16x32_bf16(pf1, *(const short8*)&Vs[n     ][32 + quad*8], o0, 0,0,0);
        o1 = __builtin_amdgcn_mfma_f32_16x16x32_bf16(pf0, *(const short8*)&Vs[16 + n][quad*8],      o1, 0,0,0);
        o1 = __builtin_amdgcn_mfma_f32_16x16x32_bf16(pf1, *(const short8*)&Vs[16 + n][32 + quad*8], o1, 0,0,0);
        o2 = __builtin_amdgcn_mfma_f32_16x16x32_bf16(pf0, *(const short8*)&Vs[32 + n][quad*8],      o2, 0,0,0);
        o2 = __builtin_amdgcn_mfma_f32_16x16x32_bf16(pf1, *(const short8*)&Vs[32 + n][32 + quad*8], o2, 0,0,0);
        o3 = __builtin_amdgcn_mfma_f32_16x16x32_bf16(pf0, *(const short8*)&Vs[48 + n][quad*8],      o3, 0,0,0);
        o3 = __builtin_amdgcn_mfma_f32_16x16x32_bf16(pf1, *(const short8*)&Vs[48 + n][32 + quad*8], o3, 0,0,0);
    }

    // epilogue: divide by l, store bf16 [B,T,D]
    #pragma unroll
    for (int r = 0; r < 4; ++r) {
        const float inv = 1.0f / l_[r];
        size_t o = ((size_t)b*T_ + q0 + quad*4 + r)*D_ + h*DK + n;
        aout[o]      = f2bf(o0[r] * inv);
        aout[o + 16] = f2bf(o1[r] * inv);
        aout[o + 32] = f2bf(o2[r] * inv);
        aout[o + 48] = f2bf(o3[r] * inv);
    }
}

// ---------------------------------------------------------------------------
// Kernel 2.5: Wp fp32 -> bf16  (1024x1024)
// ---------------------------------------------------------------------------
__global__ __launch_bounds__(256) void cvt_kernel(
    const float* __restrict__ Wp, unsigned short* __restrict__ Wb)
{
    const int i = (blockIdx.x * 256 + threadIdx.x) * 8;
    float4 a = *(const float4*)&Wp[i];
    float4 b = *(const float4*)&Wp[i + 4];
    unsigned int pk[4];
    pk[0] = f2bf(a.x) | ((unsigned)f2bf(a.y) << 16);
    pk[1] = f2bf(a.z) | ((unsigned)f2bf(a.w) << 16);
    pk[2] = f2bf(b.x) | ((unsigned)f2bf(b.y) << 16);
    pk[3] = f2bf(b.z) | ((unsigned)f2bf(b.w) << 16);
    *(uint4*)&Wb[i] = make_uint4(pk[0], pk[1], pk[2], pk[3]);
}

// ---------------------------------------------------------------------------
// Kernel 3: out = A @ Wb^T + bp.   A:[4096,1024] bf16, Wb:[1024,1024] bf16 (B^T)
// grid (32, 8), block 256 = 4 waves (2x2); 128x128 tile, BK=64.
// m97 pattern: global_load_lds width-16 staging + 16x16x32 bf16 MFMA.
// ---------------------------------------------------------------------------
__global__ __launch_bounds__(256) void proj_kernel(
    const unsigned short* __restrict__ A, const unsigned short* __restrict__ Wb,
    const float* __restrict__ bp, float* __restrict__ out)
{
    __shared__ unsigned short As[128*64];   // [row][k] unpadded (global_load_lds order)
    __shared__ unsigned short Bs[128*64];   // [col][k]

    const int m0 = blockIdx.x * 128, n0 = blockIdx.y * 128;
    const int tid = threadIdx.x;
    const int wave = tid >> 6, lane = tid & 63;
    const int wm = wave & 1, wn = wave >> 1;        // 2x2 wave grid
    const int n = lane & 15, quad = lane >> 4;

    // staging geometry: per instr a wave covers 8 rows x 64 cols (512 elem)
    const int srow = wave*32 + (lane >> 3);          // + i*8
    const int scol = (lane & 7) * 8;
    const unsigned short* ag = &A [(size_t)(m0 + srow)*1024 + scol];
    const unsigned short* bg = &Wb[(size_t)(n0 + srow)*1024 + scol];
    unsigned short* al = &As[(size_t)srow*64 + scol];
    unsigned short* bl = &Bs[(size_t)srow*64 + scol];

    fragC acc[4][4];
    #pragma unroll
    for (int i = 0; i < 4; ++i)
        #pragma unroll
        for (int j = 0; j < 4; ++j) acc[i][j] = (fragC){0.f,0.f,0.f,0.f};

    for (int kt = 0; kt < 16; ++kt) {
        __syncthreads();
        #pragma unroll
        for (int i = 0; i < 4; ++i) {
            gload_lds16(ag + (size_t)i*8*1024 + kt*64, al + i*8*64);
            gload_lds16(bg + (size_t)i*8*1024 + kt*64, bl + i*8*64);
        }
        __syncthreads();

        #pragma unroll
        for (int kk = 0; kk < 2; ++kk) {
            short8 af[4], bf[4];
            #pragma unroll
            for (int i = 0; i < 4; ++i)
                af[i] = *(const short8*)&As[(wm*64 + i*16 + n)*64 + kk*32 + quad*8];
            #pragma unroll
            for (int j = 0; j < 4; ++j)
                bf[j] = *(const short8*)&Bs[(wn*64 + j*16 + n)*64 + kk*32 + quad*8];
            #pragma unroll
            for (int i = 0; i < 4; ++i)
                #pragma unroll
                for (int j = 0; j < 4; ++j)
                    acc[i][j] = __builtin_amdgcn_mfma_f32_16x16x32_bf16(af[i], bf[j], acc[i][j], 0,0,0);
        }
    }

    // epilogue: C/D layout col=lane&15, row=quad*4+r
    #pragma unroll
    for (int i = 0; i < 4; ++i) {
        #pragma unroll
        for (int r = 0; r < 4; ++r) {
            const int m = m0 + wm*64 + i*16 + quad*4 + r;
            #pragma unroll
            for (int j = 0; j < 4; ++j) {
                const int col = n0 + wn*64 + j*16 + n;
                out[(size_t)m*1024 + col] = acc[i][j][r] + bp[col];
            }
        }
    }
}

// ---------------------------------------------------------------------------
extern "C" void kernel_launch(void* const* d_in, const int* in_sizes, int n_in,
                              void* d_out, int out_size, void* d_ws, size_t ws_size,
                              hipStream_t stream)
{
    const float* x  = (const float*)d_in[0];
    const float* Wq = (const float*)d_in[1];
    const float* Wk = (const float*)d_in[2];
    const float* Wv = (const float*)d_in[3];
    const float* Wp = (const float*)d_in[4];
    const float* bp = (const float*)d_in[5];
    float* out = (float*)d_out;

    const size_t per = (size_t)BH_ * T_ * DK;       // 4,194,304 elements
    unsigned short* qws  = (unsigned short*)d_ws;   // bf16
    unsigned short* kws  = qws + per;
    unsigned short* vtws = kws + per;
    unsigned short* aws  = vtws + per;              // [B*T, D] bf16
    unsigned short* wbws = aws + per;               // Wp bf16 [1024*1024]

    qkv_kernel<<<dim3(BH_, T_/64), 256, 0, stream>>>(x, Wq, Wk, Wv, qws, kws, vtws);
    attn_kernel<<<dim3(T_/64, BH_), 256, 0, stream>>>(qws, kws, vtws, aws);
    cvt_kernel<<<dim3(512), 256, 0, stream>>>(Wp, wbws);
    proj_kernel<<<dim3(32, 8), 256, 0, stream>>>(aws, wbws, bp, out);
}